// Round 4
// baseline (1069.714 us; speedup 1.0000x reference)
//
#include <hip/hip_runtime.h>
#include <stdint.h>

// SpectralConv1d: out[b,s,o,k,c] = per-mode-k complex matmul over i=0..31.
//   out_r = sum_i xr*wr - xi*wi ; out_i = sum_i xr*wi + xi*wr
// x: (8,2048,32,64,2) f32; w: (32,32,64,2) f32; out: (8,2048,32,64,2) f32.
// Min traffic 537 MB -> ~85-100us HBM floor; VALU issue floor ~66us.
//
// v3 (185us): batched ds_reads; VGPR_Count=64 proved the compiler sank the
// per-chunk w loads to their uses -> ~300cy L2 latency exposed per ii-step.
// v4 (CRASH): inline-asm global_load pinning — asm results are written
// async by HW; regalloc may copy/spill them before the drain. Abandoned.
// v5: same chunk-ahead w double-buffer, but with PLAIN loads pinned by
// __builtin_amdgcn_sched_barrier(0) after the issue block. Compiler keeps
// full dependency tracking (auto waitcnt before first use); the scheduler
// just can't sink the loads into the compute phase. POSB=4 so the register
// double-buffer fits <=128 VGPR (2 blocks/CU at __launch_bounds__(512,4)).

constexpr int D_IN   = 32;
constexpr int D_OUT  = 32;
constexpr int KMAX   = 64;
constexpr int NPOS   = 8 * 2048;      // b*s flattened
constexpr int POSB   = 4;             // positions per block
constexpr int OT     = 4;             // output channels per thread
constexpr int THREADS = 512;          // 64 k-lanes x 8 o-groups
constexpr int IC     = 4;             // i-steps staged per chunk
constexpr int NCHUNK = D_IN / IC;     // 8

typedef __attribute__((address_space(3))) uint32_t lds_u32_t;
typedef __attribute__((address_space(1))) const uint32_t glb_u32_t;

__device__ __forceinline__ void gload16(const float2* g, float2* l) {
    // async global->LDS, 16B per lane; LDS dest = wave-uniform base + lane*16
    __builtin_amdgcn_global_load_lds((glb_u32_t*)g, (lds_u32_t*)l, 16, 0, 0);
}

__global__ __launch_bounds__(THREADS, 4)
void spectral_conv1d_kernel(const float2* __restrict__ x,
                            const float2* __restrict__ w,
                            float2* __restrict__ out) {
    // 2 buffers x (4 pos x 4 i x 64 k) float2 = 2 x 8 KB
    __shared__ float2 xs[2][POSB * IC * KMAX];

    const int tid  = threadIdx.x;
    const int k    = tid & (KMAX - 1);    // lane index == k mode
    const int lane = tid & 63;
    const int wid  = tid >> 6;            // wave id 0..7 == o-group
    const int o0   = wid * OT;
    const long posBase = (long)blockIdx.x * POSB;

    // Staging: wave `wid` stages rows {r0, r0+1} of position pidx per chunk.
    // One gload16: lanes 0-31 -> row r0, lanes 32-63 -> row r0+1, 16B/lane;
    // LDS dest linear (2 contiguous rows = 1KB).
    const int pidx = wid >> 1;
    const int r0   = (wid & 1) * 2;
    const float2* xrow = x + (posBase + pidx) * (D_IN * KMAX)
                           + (long)(r0 + (lane >> 5)) * KMAX + (lane & 31) * 2;
    const float2* wb   = w + (long)o0 * (D_IN * KMAX) + k;

    float2 acc[POSB][OT];
    #pragma unroll
    for (int p = 0; p < POSB; ++p)
        #pragma unroll
        for (int j = 0; j < OT; ++j) acc[p][j] = make_float2(0.f, 0.f);

    #define STAGE(buf, c) \
        gload16(xrow + (long)(c) * IC * KMAX, &xs[buf][(pidx * IC + r0) * KMAX])

    // Plain loads; issue order pinned by sched_barrier(0) at the call site.
    #define WCHUNK(dst, c) do {                                             \
        _Pragma("unroll") for (int ii = 0; ii < IC; ++ii)                   \
            _Pragma("unroll") for (int j = 0; j < OT; ++j)                  \
                dst[ii][j] = wb[(j * D_IN + (c) * IC + ii) * KMAX];         \
    } while (0)

    #define COMPUTE(buf, wreg) do {                                         \
        _Pragma("unroll") for (int ii = 0; ii < IC; ++ii) {                 \
            float2 xv[POSB];                                                \
            _Pragma("unroll") for (int p = 0; p < POSB; ++p)                \
                xv[p] = xs[buf][(p * IC + ii) * KMAX + k];                  \
            _Pragma("unroll") for (int p = 0; p < POSB; ++p)                \
                _Pragma("unroll") for (int j = 0; j < OT; ++j) {            \
                    acc[p][j].x = fmaf(xv[p].x,  wreg[ii][j].x, acc[p][j].x); \
                    acc[p][j].x = fmaf(-xv[p].y, wreg[ii][j].y, acc[p][j].x); \
                    acc[p][j].y = fmaf(xv[p].x,  wreg[ii][j].y, acc[p][j].y); \
                    acc[p][j].y = fmaf(xv[p].y,  wreg[ii][j].x, acc[p][j].y); \
                }                                                           \
        }                                                                   \
    } while (0)

    // Prologue: stage chunk 0 (x -> LDS, w -> regs), drain, sync.
    float2 wA[IC][OT], wB[IC][OT];
    STAGE(0, 0);
    WCHUNK(wA, 0);
    asm volatile("s_waitcnt vmcnt(0)" ::: "memory");
    __syncthreads();

    for (int t = 0; t < NCHUNK / 2; ++t) {
        // Phase A: issue prefetch of chunk 2t+1 (x->LDS buf1, w->wB), then
        // compute chunk 2t from buf0/wA. sched_barrier(0) pins the issue
        // slots — the scheduler cannot sink the loads into/past COMPUTE.
        STAGE(1, 2 * t + 1);
        WCHUNK(wB, 2 * t + 1);
        __builtin_amdgcn_sched_barrier(0);
        COMPUTE(0, wA);
        asm volatile("s_waitcnt vmcnt(0)" ::: "memory");  // prefetch landed
        __syncthreads();

        // Phase B: prefetch chunk 2t+2 into buf0/wA, compute 2t+1.
        if (t != NCHUNK / 2 - 1) {
            STAGE(0, 2 * t + 2);
            WCHUNK(wA, 2 * t + 2);
        }
        __builtin_amdgcn_sched_barrier(0);
        COMPUTE(1, wB);
        asm volatile("s_waitcnt vmcnt(0)" ::: "memory");
        __syncthreads();
    }

    #undef STAGE
    #undef WCHUNK
    #undef COMPUTE

    float2* ob = out + posBase * (D_OUT * KMAX) + k;
    #pragma unroll
    for (int p = 0; p < POSB; ++p)
        #pragma unroll
        for (int j = 0; j < OT; ++j)
            ob[((long)p * D_OUT + o0 + j) * KMAX] = acc[p][j];
}

extern "C" void kernel_launch(void* const* d_in, const int* in_sizes, int n_in,
                              void* d_out, int out_size, void* d_ws, size_t ws_size,
                              hipStream_t stream) {
    const float2* x = (const float2*)d_in[0];
    const float2* w = (const float2*)d_in[1];
    float2* out     = (float2*)d_out;

    dim3 grid(NPOS / POSB);   // 4096 blocks
    spectral_conv1d_kernel<<<grid, THREADS, 0, stream>>>(x, w, out);
}

// Round 5
// 479.740 us; speedup vs baseline: 2.2298x; 2.2298x over previous
//
#include <hip/hip_runtime.h>
#include <stdint.h>

// SpectralConv1d: out[b,s,o,k,c] = per-mode-k complex matmul over i=0..31.
//   out_r = sum_i xr*wr - xi*wi ; out_i = sum_i xr*wi + xi*wr
// x: (8,2048,32,64,2) f32; w: (32,32,64,2) f32; out: (8,2048,32,64,2) f32.
// Min traffic 537 MB -> ~85-100us HBM floor; VALU issue floor ~66us.
//
// v3 (185us): x staged via global_load_lds dbuf + batched ds_reads. Residual:
// VGPR_Count=64 -> compiler sank the chunk-top w loads to their uses
// (pressure-limited scheduling at its 8-waves/EU budget) -> ~300cy L2
// latency exposed per ii-step.
// v4/v5 (fail): forcing the hoist via asm loads / sched_barrier at a 64-reg
// budget -> regalloc spilled to scratch (v5: WRITE 262MB->1.74GB, 780us).
// v6: identical body to v3; ONE change: amdgpu_waves_per_eu(4,4). max=4
// removes the occupancy incentive for the 64-reg budget -> true 128-reg
// budget -> scheduler keeps the w loads hoisted at chunk top (no pressure
// motive to sink), no spills. 2 blocks/CU, 16 waves/CU.

constexpr int D_IN   = 32;
constexpr int D_OUT  = 32;
constexpr int KMAX   = 64;
constexpr int NPOS   = 8 * 2048;      // b*s flattened
constexpr int POSB   = 8;             // positions per block == waves per block
constexpr int OT     = 4;             // output channels per thread
constexpr int THREADS = 512;          // 64 k-lanes x 8 o-groups
constexpr int IC     = 4;             // i-steps staged per chunk
constexpr int NCHUNK = D_IN / IC;     // 8

typedef __attribute__((address_space(3))) uint32_t lds_u32_t;
typedef __attribute__((address_space(1))) const uint32_t glb_u32_t;

__device__ __forceinline__ void gload16(const float2* g, float2* l) {
    // async global->LDS, 16B per lane; LDS dest = wave-uniform base + lane*16
    __builtin_amdgcn_global_load_lds((glb_u32_t*)g, (lds_u32_t*)l, 16, 0, 0);
}

__global__ __launch_bounds__(THREADS)
__attribute__((amdgpu_waves_per_eu(4, 4)))
void spectral_conv1d_kernel(const float2* __restrict__ x,
                            const float2* __restrict__ w,
                            float2* __restrict__ out) {
    // 2 buffers x (8 pos x 4 i x 64 k) float2 = 2 x 16 KB
    __shared__ float2 xs[2][POSB * IC * KMAX];

    const int tid  = threadIdx.x;
    const int k    = tid & (KMAX - 1);    // lane index == k mode
    const int lane = tid & 63;
    const int wid  = tid >> 6;            // wave id 0..7 == o-group == staged pos
    const int o0   = wid * OT;
    const long posBase = (long)blockIdx.x * POSB;

    float2 acc[POSB][OT];
    #pragma unroll
    for (int p = 0; p < POSB; ++p)
        #pragma unroll
        for (int j = 0; j < OT; ++j) acc[p][j] = make_float2(0.f, 0.f);

    // Staging: wave `wid` stages position posBase+wid. Chunk = 4 i-rows of
    // 512B each, contiguous 2KB in global. One gload16 covers 2 rows:
    // lanes 0-31 -> row ii, lanes 32-63 -> row ii+1; LDS dest linear.
    const float2* xrow = x + (posBase + wid) * (D_IN * KMAX)
                           + (long)(lane >> 5) * KMAX + (lane & 31) * 2;
    const float2* wb   = w + (long)o0 * (D_IN * KMAX) + k;

    #define STAGE(buf, c) do {                                              \
        const float2* s0_ = xrow + (long)(c) * IC * KMAX;                   \
        gload16(s0_,            &xs[buf][(wid * IC + 0) * KMAX]);           \
        gload16(s0_ + 2 * KMAX, &xs[buf][(wid * IC + 2) * KMAX]);           \
    } while (0)

    STAGE(0, 0);
    asm volatile("s_waitcnt vmcnt(0)" ::: "memory");
    __syncthreads();

    for (int c = 0; c < NCHUNK; ++c) {
        const int cur = c & 1;
        if (c + 1 < NCHUNK) STAGE(cur ^ 1, c + 1);   // prefetch next chunk

        const int i0 = c * IC;

        // Hoist ALL w loads for this chunk: 16 float2 = 32 VGPR, issued
        // back-to-back at chunk top. With the (4,4) reg budget the scheduler
        // has no pressure motive to sink them -> L2 latency exposed at most
        // once per chunk instead of per ii-step.
        float2 wreg[IC][OT];
        #pragma unroll
        for (int ii = 0; ii < IC; ++ii)
            #pragma unroll
            for (int j = 0; j < OT; ++j)
                wreg[ii][j] = wb[(j * D_IN + i0 + ii) * KMAX];

        #pragma unroll
        for (int ii = 0; ii < IC; ++ii) {
            // Batch the 8 LDS reads before the FMA block: back-to-back
            // ds_read_b64, lgkm latency amortized over the batch.
            float2 xv[POSB];
            #pragma unroll
            for (int p = 0; p < POSB; ++p)
                xv[p] = xs[cur][(p * IC + ii) * KMAX + k];

            #pragma unroll
            for (int p = 0; p < POSB; ++p) {
                #pragma unroll
                for (int j = 0; j < OT; ++j) {
                    acc[p][j].x = fmaf(xv[p].x,  wreg[ii][j].x, acc[p][j].x);
                    acc[p][j].x = fmaf(-xv[p].y, wreg[ii][j].y, acc[p][j].x);
                    acc[p][j].y = fmaf(xv[p].x,  wreg[ii][j].y, acc[p][j].y);
                    acc[p][j].y = fmaf(xv[p].y,  wreg[ii][j].x, acc[p][j].y);
                }
            }
        }

        asm volatile("s_waitcnt vmcnt(0)" ::: "memory");  // staged loads landed
        __syncthreads();                                   // all waves done w/ cur
    }
    #undef STAGE

    float2* ob = out + posBase * (D_OUT * KMAX) + k;
    #pragma unroll
    for (int p = 0; p < POSB; ++p)
        #pragma unroll
        for (int j = 0; j < OT; ++j)
            ob[((long)p * D_OUT + o0 + j) * KMAX] = acc[p][j];
}

extern "C" void kernel_launch(void* const* d_in, const int* in_sizes, int n_in,
                              void* d_out, int out_size, void* d_ws, size_t ws_size,
                              hipStream_t stream) {
    const float2* x = (const float2*)d_in[0];
    const float2* w = (const float2*)d_in[1];
    float2* out     = (float2*)d_out;

    dim3 grid(NPOS / POSB);   // 2048 blocks
    spectral_conv1d_kernel<<<grid, THREADS, 0, stream>>>(x, w, out);
}